// Round 1
// baseline (397.581 us; speedup 1.0000x reference)
//
#include <hip/hip_runtime.h>
#include <hip/hip_bf16.h>

typedef __attribute__((ext_vector_type(8))) short short8;
typedef __attribute__((ext_vector_type(4))) float f32x4;

__device__ inline short f2bf(float x) {
    union { __hip_bfloat16 b; short s; } u;
    u.b = __float2bfloat16(x);
    return u.s;
}

// ---------------- transpose + f32->bf16 convert ----------------
// in [R][C] f32 (row-major) -> out [n][R] bf16 for n in [0,Cp); cols >= C read as 0.
__global__ void transpose_cvt(const float* __restrict__ in, short* __restrict__ out,
                              int R, int C, int Cp) {
    __shared__ float tile[32][33];
    int r0 = blockIdx.x * 32;
    int c0 = blockIdx.y * 32;
    int tr = threadIdx.x >> 5;   // 0..7
    int tc = threadIdx.x & 31;
    #pragma unroll
    for (int i = 0; i < 4; ++i) {
        int r = r0 + tr + i * 8;          // r < R guaranteed (R multiple of 32, grid exact)
        int c = c0 + tc;
        float v = 0.f;
        if (c < C) v = in[(long)r * C + c];
        tile[tr + i * 8][tc] = v;
    }
    __syncthreads();
    #pragma unroll
    for (int i = 0; i < 4; ++i) {
        int n = c0 + tr + i * 8;          // output row (former col)
        int k = r0 + tc;                  // output col (former row)
        if (n < Cp) out[(long)n * R + k] = f2bf(tile[tc][tr + i * 8]);
    }
}

__global__ void make_bias_h(const float* __restrict__ bc, const float* __restrict__ bb,
                            float* __restrict__ bh) {
    int i = threadIdx.x;  // 448 threads
    float v = 0.f;
    if (i < 81) v = bc[i];
    else if (i < 405) v = bb[i - 81];
    bh[i] = v;
}

// ---------------- ROI-align -> X bf16 [1024][12544] ----------------
__global__ void roi_align_kernel(const float* __restrict__ feat,   // [2][256][50][50]
                                 const float* __restrict__ props,  // [2][512][4]
                                 short* __restrict__ Xb) {
    int roi = blockIdx.x;  // 0..1023
    int img = roi >> 9;
    __shared__ int   soff[196];
    __shared__ int   sdx[196];
    __shared__ int   sdy[196];
    __shared__ float w00s[196], w01s[196], w10s[196], w11s[196];
    __shared__ float pbox[4];
    int tid = threadIdx.x;
    if (tid < 4) pbox[tid] = props[roi * 4 + tid];
    __syncthreads();
    if (tid < 196) {
        float x1 = pbox[0] * 0.0625f, y1 = pbox[1] * 0.0625f;
        float x2 = pbox[2] * 0.0625f, y2 = pbox[3] * 0.0625f;
        float rw = fmaxf(x2 - x1, 1.0f), rh = fmaxf(y2 - y1, 1.0f);
        int p = tid >> 2, q = tid & 3;
        int py = p / 7, px = p % 7;
        int sy = q >> 1, sx = q & 1;
        int gy = py * 2 + sy, gx = px * 2 + sx;
        float gyv = ((float)gy + 0.5f) * 0.5f;  // (g+0.5)/SR, SR=2
        float gxv = ((float)gx + 0.5f) * 0.5f;
        float ys = y1 + gyv * (rh * (1.0f / 7.0f));
        float xs = x1 + gxv * (rw * (1.0f / 7.0f));
        ys = fminf(fmaxf(ys, 0.0f), 49.0f);
        xs = fminf(fmaxf(xs, 0.0f), 49.0f);
        float y0f = floorf(ys), x0f = floorf(xs);
        int y0 = (int)y0f, x0 = (int)x0f;
        int y1i = min(y0 + 1, 49), x1i = min(x0 + 1, 49);
        float ly = ys - y0f, lx = xs - x0f;
        float hy = 1.f - ly, hx = 1.f - lx;
        soff[tid] = y0 * 50 + x0;
        sdx[tid] = x1i - x0;
        sdy[tid] = (y1i - y0) * 50;
        w00s[tid] = hy * hx; w01s[tid] = hy * lx;
        w10s[tid] = ly * hx; w11s[tid] = ly * lx;
    }
    __syncthreads();
    const float* fb = feat + (long)img * 256 * 2500;
    for (int e = tid; e < 12544; e += 256) {
        int c = e / 49, p = e % 49;
        const float* fc = fb + c * 2500;
        float acc = 0.f;
        #pragma unroll
        for (int q = 0; q < 4; ++q) {
            int s = p * 4 + q;
            int o = soff[s], dx = sdx[s], dy = sdy[s];
            float f00 = fc[o], f01 = fc[o + dx], f10 = fc[o + dy], f11 = fc[o + dy + dx];
            acc += w00s[s] * f00 + w01s[s] * f01 + w10s[s] * f10 + w11s[s] * f11;
        }
        Xb[(long)roi * 12544 + e] = f2bf(acc * 0.25f);
    }
}

// ---------------- bf16 MFMA GEMM: C = A[M,K] @ Bt[N,K]^T + bias ----------------
template <int RELU, int OBF16>
__global__ __launch_bounds__(256) void gemm_bt(const short* __restrict__ A,
                                               const short* __restrict__ Bt,
                                               const float* __restrict__ bias,
                                               void* __restrict__ Cout,
                                               int M, int N, int K) {
    __shared__ short As[64 * 72];
    __shared__ short Bs[64 * 72];
    int m0 = blockIdx.y * 64, n0 = blockIdx.x * 64;
    int tid = threadIdx.x;
    int r = tid >> 2, seg = tid & 3;
    int w = tid >> 6, lane = tid & 63;
    int wr = w >> 1, wc = w & 1;
    int lr = lane & 15, lk = lane >> 4;
    f32x4 acc[2][2] = {};
    const short8* Ag = (const short8*)(A + (long)(m0 + r) * K + seg * 16);
    const short8* Bg = (const short8*)(Bt + (long)(n0 + r) * K + seg * 16);
    short8* AsW = (short8*)&As[r * 72 + seg * 16];
    short8* BsW = (short8*)&Bs[r * 72 + seg * 16];
    for (int k0 = 0; k0 < K; k0 += 64) {
        short8 a0 = Ag[0], a1 = Ag[1];
        short8 b0 = Bg[0], b1 = Bg[1];
        Ag += 8; Bg += 8;
        AsW[0] = a0; AsW[1] = a1;
        BsW[0] = b0; BsW[1] = b1;
        __syncthreads();
        #pragma unroll
        for (int kk = 0; kk < 2; ++kk) {
            short8 af0 = *(const short8*)&As[(wr * 32 + 0 + lr) * 72 + kk * 32 + lk * 8];
            short8 af1 = *(const short8*)&As[(wr * 32 + 16 + lr) * 72 + kk * 32 + lk * 8];
            short8 bf0 = *(const short8*)&Bs[(wc * 32 + 0 + lr) * 72 + kk * 32 + lk * 8];
            short8 bf1 = *(const short8*)&Bs[(wc * 32 + 16 + lr) * 72 + kk * 32 + lk * 8];
            acc[0][0] = __builtin_amdgcn_mfma_f32_16x16x32_bf16(af0, bf0, acc[0][0], 0, 0, 0);
            acc[0][1] = __builtin_amdgcn_mfma_f32_16x16x32_bf16(af0, bf1, acc[0][1], 0, 0, 0);
            acc[1][0] = __builtin_amdgcn_mfma_f32_16x16x32_bf16(af1, bf0, acc[1][0], 0, 0, 0);
            acc[1][1] = __builtin_amdgcn_mfma_f32_16x16x32_bf16(af1, bf1, acc[1][1], 0, 0, 0);
        }
        __syncthreads();
    }
    #pragma unroll
    for (int fm = 0; fm < 2; ++fm) {
        #pragma unroll
        for (int fn = 0; fn < 2; ++fn) {
            int col = n0 + wc * 32 + fn * 16 + lr;
            float bv = bias[col];
            #pragma unroll
            for (int j = 0; j < 4; ++j) {
                int row = m0 + wr * 32 + fm * 16 + lk * 4 + j;
                float v = acc[fm][fn][j] + bv;
                if (RELU) v = fmaxf(v, 0.f);
                if (OBF16) ((short*)Cout)[(long)row * N + col] = f2bf(v);
                else       ((float*)Cout)[(long)row * N + col] = v;
            }
        }
    }
}

// ---------------- softmax + decode + valid ----------------
__global__ void head_epilogue(const float* __restrict__ O,      // [1024][448]
                              const float* __restrict__ props,  // [2][512][4]
                              float* __restrict__ Boxes,        // [2][40960][4]
                              float* __restrict__ Scores,       // [2][40960]
                              unsigned char* __restrict__ Valid) {
    int roi = blockIdx.x;
    int lane = threadIdx.x;  // 64
    const float* o = O + (long)roi * 448;
    float m = -1e30f;
    for (int i = lane; i < 81; i += 64) m = fmaxf(m, o[i]);
    for (int off = 32; off > 0; off >>= 1) m = fmaxf(m, __shfl_xor(m, off));
    float ssum = 0.f;
    for (int i = lane; i < 81; i += 64) ssum += expf(o[i] - m);
    for (int off = 32; off > 0; off >>= 1) ssum += __shfl_xor(ssum, off);
    float inv = 1.0f / ssum;
    int img = roi >> 9, rb = roi & 511;
    float px1 = props[roi * 4 + 0], py1 = props[roi * 4 + 1];
    float px2 = props[roi * 4 + 2], py2 = props[roi * 4 + 3];
    float w = px2 - px1, h = py2 - py1;
    float cx = px1 + 0.5f * w, cy = py1 + 0.5f * h;
    long obase = (long)img * 40960 + (long)rb * 80;
    const float DW = 4.135166556742356f;
    for (int t = lane; t < 80; t += 64) {
        int cls = t + 1;
        float score = expf(o[cls] - m) * inv;
        const float* d = o + 81 + cls * 4;
        float dx = d[0] * 0.1f, dy = d[1] * 0.1f;
        float dw = fminf(d[2] * 0.2f, DW);
        float dh = fminf(d[3] * 0.2f, DW);
        float pcx = dx * w + cx, pcy = dy * h + cy;
        float pw = expf(dw) * w, ph = expf(dh) * h;
        float x1 = pcx - 0.5f * pw, y1 = pcy - 0.5f * ph;
        float x2 = pcx + 0.5f * pw, y2 = pcy + 0.5f * ph;
        x1 = fminf(fmaxf(x1, 0.f), 800.f); y1 = fminf(fmaxf(y1, 0.f), 800.f);
        x2 = fminf(fmaxf(x2, 0.f), 800.f); y2 = fminf(fmaxf(y2, 0.f), 800.f);
        float wv = x2 - x1, hv = y2 - y1;
        long oi = obase + t;
        Boxes[oi * 4 + 0] = x1; Boxes[oi * 4 + 1] = y1;
        Boxes[oi * 4 + 2] = x2; Boxes[oi * 4 + 3] = y2;
        Scores[oi] = score;
        Valid[oi] = (score >= 0.05f && wv >= 1.0f && hv >= 1.0f) ? 1 : 0;
    }
}

// ---------------- order-stable compaction (per image) ----------------
__global__ void compact_kernel(const float* __restrict__ Boxes, const float* __restrict__ Scores,
                               const unsigned char* __restrict__ Valid,
                               float* __restrict__ CB, float* __restrict__ CS,
                               int* __restrict__ CL, int* __restrict__ CCnt) {
    int img = blockIdx.x;
    int tid = threadIdx.x;  // 256
    int wid = tid >> 6, lane = tid & 63;
    __shared__ int wcnt[4];
    __shared__ int base_s;
    if (tid == 0) base_s = 0;
    __syncthreads();
    const float* B = Boxes + (long)img * 40960 * 4;
    const float* S = Scores + (long)img * 40960;
    const unsigned char* V = Valid + (long)img * 40960;
    float* cb = CB + (long)img * 40960 * 4;
    float* cs = CS + (long)img * 40960;
    int* cl = CL + (long)img * 40960;
    for (int c0 = 0; c0 < 40960; c0 += 256) {
        int j = c0 + tid;
        int valid = V[j] ? 1 : 0;
        unsigned long long mask = __ballot(valid);
        if (lane == 0) wcnt[wid] = __popcll(mask);
        __syncthreads();
        int base = base_s;
        int woff = 0;
        for (int i = 0; i < wid; ++i) woff += wcnt[i];
        if (valid) {
            int pos = base + woff + __popcll(mask & ((1ull << lane) - 1ull));
            cs[pos] = S[j];
            cb[pos * 4 + 0] = B[j * 4 + 0]; cb[pos * 4 + 1] = B[j * 4 + 1];
            cb[pos * 4 + 2] = B[j * 4 + 2]; cb[pos * 4 + 3] = B[j * 4 + 3];
            cl[pos] = (j % 80) + 1;
        }
        __syncthreads();
        if (tid == 0) base_s = base + wcnt[0] + wcnt[1] + wcnt[2] + wcnt[3];
        __syncthreads();
    }
    if (tid == 0) CCnt[img] = base_s;
}

// ---------------- greedy NMS + final output (per image) ----------------
__global__ void nms_kernel(const float* __restrict__ CB, const float* __restrict__ CS_in,
                           const int* __restrict__ CL, const int* __restrict__ CCnt,
                           float* __restrict__ out, float* __restrict__ cs_work) {
    int img = blockIdx.x;
    int tid = threadIdx.x;  // 256
    int V = CCnt[img];
    const float* cb = CB + (long)img * 40960 * 4;
    const int* cl = CL + (long)img * 40960;
    const float* csin = CS_in + (long)img * 40960;
    float* sc = cs_work + (long)img * 40960;
    const float NEG = -__builtin_inff();
    for (int j = tid; j < V; j += 256) sc[j] = csin[j];
    // zero this image's output slice: boxes@0, scores@800, labels@1000, ok@1200
    for (int i = tid; i < 400; i += 256) out[img * 400 + i] = 0.f;
    if (tid < 100) {
        out[800 + img * 100 + tid] = 0.f;
        out[1000 + img * 100 + tid] = 0.f;
        out[1200 + img * 100 + tid] = 0.f;
    }
    __syncthreads();
    __shared__ float rv[256];
    __shared__ int ri[256];
    __shared__ float selbox[4];
    for (int det = 0; det < 100; ++det) {
        float bv = NEG; int bi = -1;
        for (int j = tid; j < V; j += 256) {
            float s = sc[j];
            if (s > bv) { bv = s; bi = j; }
        }
        rv[tid] = bv; ri[tid] = bi;
        __syncthreads();
        for (int off = 128; off > 0; off >>= 1) {
            if (tid < off) {
                float ov = rv[tid + off]; int oi = ri[tid + off];
                if (ov > rv[tid] ||
                    (ov == rv[tid] && oi != -1 && (ri[tid] == -1 || oi < ri[tid]))) {
                    rv[tid] = ov; ri[tid] = oi;
                }
            }
            __syncthreads();
        }
        float mval = rv[0]; int mi = ri[0];
        if (!(mval > NEG) || mi < 0) break;
        if (tid == 0) {
            out[img * 400 + det * 4 + 0] = cb[mi * 4 + 0];
            out[img * 400 + det * 4 + 1] = cb[mi * 4 + 1];
            out[img * 400 + det * 4 + 2] = cb[mi * 4 + 2];
            out[img * 400 + det * 4 + 3] = cb[mi * 4 + 3];
            out[800 + img * 100 + det] = mval;
            out[1000 + img * 100 + det] = (float)cl[mi];
            out[1200 + img * 100 + det] = 1.0f;
            selbox[0] = cb[mi * 4 + 0]; selbox[1] = cb[mi * 4 + 1];
            selbox[2] = cb[mi * 4 + 2]; selbox[3] = cb[mi * 4 + 3];
            sc[mi] = NEG;
        }
        __syncthreads();
        float bx1 = selbox[0], by1 = selbox[1], bx2 = selbox[2], by2 = selbox[3];
        float a1 = (bx2 - bx1) * (by2 - by1);
        for (int j = tid; j < V; j += 256) {
            float s = sc[j];
            if (s == NEG) continue;
            float x1 = fmaxf(bx1, cb[j * 4 + 0]), y1 = fmaxf(by1, cb[j * 4 + 1]);
            float x2 = fminf(bx2, cb[j * 4 + 2]), y2 = fminf(by2, cb[j * 4 + 3]);
            float iw = fmaxf(x2 - x1, 0.f), ih = fmaxf(y2 - y1, 0.f);
            float inter = iw * ih;
            float a2 = (cb[j * 4 + 2] - cb[j * 4 + 0]) * (cb[j * 4 + 3] - cb[j * 4 + 1]);
            float iou = inter / (a1 + a2 - inter + 1e-9f);
            if (iou > 0.5f) sc[j] = NEG;
        }
        __syncthreads();
    }
}

extern "C" void kernel_launch(void* const* d_in, const int* in_sizes, int n_in,
                              void* d_out, int out_size, void* d_ws, size_t ws_size,
                              hipStream_t stream) {
    const float* features  = (const float*)d_in[0];
    const float* proposals = (const float*)d_in[1];
    const float* W1 = (const float*)d_in[2];
    const float* b1 = (const float*)d_in[3];
    const float* W2 = (const float*)d_in[4];
    const float* b2 = (const float*)d_in[5];
    const float* Wc = (const float*)d_in[6];
    const float* bc = (const float*)d_in[7];
    const float* Wb = (const float*)d_in[8];
    const float* bb = (const float*)d_in[9];

    const size_t MB = 1024 * 1024;
    char* ws = (char*)d_ws;
    // region A (0..26MB): Xb during phase 1, reused after GEMM1
    short* Xb     = (short*)(ws);                 // 25.7MB
    short* H2b    = (short*)(ws);                 // 2MB (after Xb dead)
    float* Obuf   = (float*)(ws + 4 * MB);        // 1.84MB
    float* Boxes  = (float*)(ws + 8 * MB);        // 1.31MB
    float* Scores = (float*)(ws + 10 * MB);       // 0.33MB
    unsigned char* Valid = (unsigned char*)(ws + 11 * MB);  // 80KB
    float* CB     = (float*)(ws + 12 * MB);       // 1.31MB
    float* CS     = (float*)(ws + 14 * MB);       // 0.33MB
    int*   CL     = (int*)(ws + 15 * MB);         // 0.33MB
    float* CSw    = (float*)(ws + 16 * MB);       // 0.33MB
    int*   CCnt   = (int*)(ws + 17 * MB);
    short* W1t    = (short*)(ws + 26 * MB);       // 25.7MB
    short* W2t    = (short*)(ws + 52 * MB);       // 2MB
    short* Wht    = (short*)(ws + 54 * MB);       // 0.92MB (448x1024 bf16)
    float* biash  = (float*)(ws + 55 * MB);       // 1.8KB
    short* H1b    = (short*)(ws + 56 * MB);       // 2MB  (total need ~58MB)

    // weights: transpose + convert to bf16 (K-contiguous B^T layout)
    transpose_cvt<<<dim3(12544 / 32, 1024 / 32), 256, 0, stream>>>(W1, W1t, 12544, 1024, 1024);
    transpose_cvt<<<dim3(1024 / 32, 1024 / 32), 256, 0, stream>>>(W2, W2t, 1024, 1024, 1024);
    transpose_cvt<<<dim3(1024 / 32, 448 / 32), 256, 0, stream>>>(Wc, Wht, 1024, 81, 448);
    transpose_cvt<<<dim3(1024 / 32, 11), 256, 0, stream>>>(Wb, Wht + 81 * 1024, 1024, 324, 324);
    make_bias_h<<<1, 448, 0, stream>>>(bc, bb, biash);

    roi_align_kernel<<<1024, 256, 0, stream>>>(features, proposals, Xb);

    gemm_bt<1, 1><<<dim3(16, 16), 256, 0, stream>>>(Xb, W1t, b1, (void*)H1b, 1024, 1024, 12544);
    gemm_bt<1, 1><<<dim3(16, 16), 256, 0, stream>>>(H1b, W2t, b2, (void*)H2b, 1024, 1024, 1024);
    gemm_bt<0, 0><<<dim3(7, 16), 256, 0, stream>>>(H2b, Wht, biash, (void*)Obuf, 1024, 448, 1024);

    head_epilogue<<<1024, 64, 0, stream>>>(Obuf, proposals, Boxes, Scores, Valid);
    compact_kernel<<<2, 256, 0, stream>>>(Boxes, Scores, Valid, CB, CS, CL, CCnt);
    nms_kernel<<<2, 256, 0, stream>>>(CB, CS, CL, CCnt, (float*)d_out, CSw);
}

// Round 2
// 187.994 us; speedup vs baseline: 2.1149x; 2.1149x over previous
//
#include <hip/hip_runtime.h>
#include <hip/hip_bf16.h>

typedef __attribute__((ext_vector_type(8))) short short8;
typedef __attribute__((ext_vector_type(4))) float f32x4;

__device__ inline short f2bf(float x) {
    union { __hip_bfloat16 b; short s; } u;
    u.b = __float2bfloat16(x);
    return u.s;
}
__device__ inline float bf2f(short s) {
    union { __hip_bfloat16 b; short s; } u;
    u.s = s;
    return __bfloat162float(u.b);
}

// ---------------- transpose + f32->bf16 convert ----------------
// in [R][C] f32 (row-major) -> out [n][R] bf16 for n in [0,Cp); cols >= C read as 0.
// grid.x = R/32 (exact), grid.y = ceil(Cp/32)
__global__ void transpose_cvt(const float* __restrict__ in, short* __restrict__ out,
                              int R, int C, int Cp) {
    __shared__ float tile[32][33];
    int r0 = blockIdx.x * 32;
    int c0 = blockIdx.y * 32;
    int tr = threadIdx.x >> 5;   // 0..7
    int tc = threadIdx.x & 31;
    #pragma unroll
    for (int i = 0; i < 4; ++i) {
        int r = r0 + tr + i * 8;
        int c = c0 + tc;
        float v = 0.f;
        if (c < C) v = in[(long)r * C + c];
        tile[tr + i * 8][tc] = v;
    }
    __syncthreads();
    #pragma unroll
    for (int i = 0; i < 4; ++i) {
        int n = c0 + tr + i * 8;          // output row (former col)
        int k = r0 + tc;                  // output col (former row)
        if (n < Cp) out[(long)n * R + k] = f2bf(tile[tc][tr + i * 8]);
    }
}

__global__ void make_bias_h(const float* __restrict__ bc, const float* __restrict__ bb,
                            float* __restrict__ bh) {
    int i = threadIdx.x;  // 448 threads
    float v = 0.f;
    if (i < 81) v = bc[i];
    else if (i < 405) v = bb[i - 81];
    bh[i] = v;
}

// ---------------- ROI-align v2: channel-last bf16 features ----------------
// featT [2][2500][256] bf16 (position-major, channel contiguous)
// thread = channel; 4 corner loads per sample are coalesced and L1-resident.
__global__ __launch_bounds__(256) void roi_align_v2(const short* __restrict__ featT,
                                                    const float* __restrict__ props,
                                                    short* __restrict__ Xb) {
    int roi = blockIdx.x;  // 0..1023
    int img = roi >> 9;
    __shared__ int   sbase[196];                  // (y0*50+x0)*256
    __shared__ int   sdx[196];                    // (x1i-x0)*256
    __shared__ int   sdy[196];                    // (y1i-y0)*50*256
    __shared__ float w00s[196], w01s[196], w10s[196], w11s[196];
    __shared__ float pbox[4];
    __shared__ short outb[49 * 260];              // [p][c] staging, pad 260
    int tid = threadIdx.x;
    if (tid < 4) pbox[tid] = props[roi * 4 + tid];
    __syncthreads();
    if (tid < 196) {
        float x1 = pbox[0] * 0.0625f, y1 = pbox[1] * 0.0625f;
        float x2 = pbox[2] * 0.0625f, y2 = pbox[3] * 0.0625f;
        float rw = fmaxf(x2 - x1, 1.0f), rh = fmaxf(y2 - y1, 1.0f);
        int p = tid >> 2, q = tid & 3;
        int py = p / 7, px = p % 7;
        int sy = q >> 1, sx = q & 1;
        int gy = py * 2 + sy, gx = px * 2 + sx;
        float gyv = ((float)gy + 0.5f) * 0.5f;
        float gxv = ((float)gx + 0.5f) * 0.5f;
        float ys = y1 + gyv * (rh * (1.0f / 7.0f));
        float xs = x1 + gxv * (rw * (1.0f / 7.0f));
        ys = fminf(fmaxf(ys, 0.0f), 49.0f);
        xs = fminf(fmaxf(xs, 0.0f), 49.0f);
        float y0f = floorf(ys), x0f = floorf(xs);
        int y0 = (int)y0f, x0 = (int)x0f;
        int y1i = min(y0 + 1, 49), x1i = min(x0 + 1, 49);
        float ly = ys - y0f, lx = xs - x0f;
        float hy = 1.f - ly, hx = 1.f - lx;
        sbase[tid] = (y0 * 50 + x0) * 256;
        sdx[tid] = (x1i - x0) * 256;
        sdy[tid] = (y1i - y0) * 50 * 256;
        w00s[tid] = hy * hx; w01s[tid] = hy * lx;
        w10s[tid] = ly * hx; w11s[tid] = ly * lx;
    }
    __syncthreads();
    const short* fb = featT + (long)img * 2500 * 256 + tid;  // channel = tid
    #pragma unroll 1
    for (int p = 0; p < 49; ++p) {
        float acc = 0.f;
        #pragma unroll
        for (int q = 0; q < 4; ++q) {
            int s = p * 4 + q;
            int b = sbase[s], dx = sdx[s], dy = sdy[s];
            float f00 = bf2f(fb[b]);
            float f01 = bf2f(fb[b + dx]);
            float f10 = bf2f(fb[b + dy]);
            float f11 = bf2f(fb[b + dy + dx]);
            acc += w00s[s] * f00 + w01s[s] * f01 + w10s[s] * f10 + w11s[s] * f11;
        }
        outb[p * 260 + tid] = f2bf(acc * 0.25f);
    }
    __syncthreads();
    // coalesced write: element e = c*49+p, threads cover consecutive e
    int c = tid / 49, r = tid % 49;
    short* xrow = Xb + (long)roi * 12544;
    #pragma unroll 1
    for (int i = 0; i < 49; ++i) {
        int e = tid + i * 256;
        xrow[e] = outb[r * 260 + c];
        c += 5; r += 11;
        if (r >= 49) { r -= 49; c += 1; }
    }
}

// ---------------- bf16 MFMA GEMM: C = A[M,K] @ Bt[N,K]^T ----------------
// MODE 0: partial -> bf16 (no bias), out + blockIdx.z*M*N
// MODE 1: bias+relu -> bf16
// MODE 2: bias -> f32
template <int MODE>
__global__ __launch_bounds__(256) void gemm_bt(const short* __restrict__ A,
                                               const short* __restrict__ Bt,
                                               const float* __restrict__ bias,
                                               void* __restrict__ Cout,
                                               int M, int N, int K, int ksteps) {
    __shared__ short As[64 * 72];
    __shared__ short Bs[64 * 72];
    int m0 = blockIdx.y * 64, n0 = blockIdx.x * 64;
    long kbeg = (long)blockIdx.z * ksteps * 64;
    int tid = threadIdx.x;
    int r = tid >> 2, seg = tid & 3;
    int w = tid >> 6, lane = tid & 63;
    int wr = w >> 1, wc = w & 1;
    int lr = lane & 15, lk = lane >> 4;
    f32x4 acc[2][2] = {};
    const short8* Ag = (const short8*)(A + (long)(m0 + r) * K + kbeg + seg * 16);
    const short8* Bg = (const short8*)(Bt + (long)(n0 + r) * K + kbeg + seg * 16);
    short8* AsW = (short8*)&As[r * 72 + seg * 16];
    short8* BsW = (short8*)&Bs[r * 72 + seg * 16];
    short8 a0 = Ag[0], a1 = Ag[1];
    short8 b0 = Bg[0], b1 = Bg[1];
    for (int s = 0; s < ksteps; ++s) {
        Ag += 8; Bg += 8;
        AsW[0] = a0; AsW[1] = a1;
        BsW[0] = b0; BsW[1] = b1;
        __syncthreads();
        if (s + 1 < ksteps) {  // prefetch next k-tile while computing this one
            a0 = Ag[0]; a1 = Ag[1];
            b0 = Bg[0]; b1 = Bg[1];
        }
        #pragma unroll
        for (int kk = 0; kk < 2; ++kk) {
            short8 af0 = *(const short8*)&As[(wr * 32 + 0 + lr) * 72 + kk * 32 + lk * 8];
            short8 af1 = *(const short8*)&As[(wr * 32 + 16 + lr) * 72 + kk * 32 + lk * 8];
            short8 bf0 = *(const short8*)&Bs[(wc * 32 + 0 + lr) * 72 + kk * 32 + lk * 8];
            short8 bf1 = *(const short8*)&Bs[(wc * 32 + 16 + lr) * 72 + kk * 32 + lk * 8];
            acc[0][0] = __builtin_amdgcn_mfma_f32_16x16x32_bf16(af0, bf0, acc[0][0], 0, 0, 0);
            acc[0][1] = __builtin_amdgcn_mfma_f32_16x16x32_bf16(af0, bf1, acc[0][1], 0, 0, 0);
            acc[1][0] = __builtin_amdgcn_mfma_f32_16x16x32_bf16(af1, bf0, acc[1][0], 0, 0, 0);
            acc[1][1] = __builtin_amdgcn_mfma_f32_16x16x32_bf16(af1, bf1, acc[1][1], 0, 0, 0);
        }
        __syncthreads();
    }
    #pragma unroll
    for (int fm = 0; fm < 2; ++fm) {
        #pragma unroll
        for (int fn = 0; fn < 2; ++fn) {
            int col = n0 + wc * 32 + fn * 16 + lr;
            #pragma unroll
            for (int j = 0; j < 4; ++j) {
                int row = m0 + wr * 32 + fm * 16 + lk * 4 + j;
                float v = acc[fm][fn][j];
                if (MODE == 0) {
                    ((short*)Cout)[(long)blockIdx.z * M * N + (long)row * N + col] = f2bf(v);
                } else {
                    v += bias[col];
                    if (MODE == 1) ((short*)Cout)[(long)row * N + col] = f2bf(fmaxf(v, 0.f));
                    else           ((float*)Cout)[(long)row * N + col] = v;
                }
            }
        }
    }
}

// ---------------- split-K reduce: H1 = relu(sum_s P[s] + b1) -> bf16 ----------------
__global__ void reduce4_relu(const short* __restrict__ P, const float* __restrict__ bias,
                             short* __restrict__ Hout) {
    long i0 = ((long)blockIdx.x * 256 + threadIdx.x) * 8;   // 1M elements / 8
    int col = (int)(i0 & 1023);
    short8 p0 = *(const short8*)(P + i0);
    short8 p1 = *(const short8*)(P + 1048576 + i0);
    short8 p2 = *(const short8*)(P + 2097152 + i0);
    short8 p3 = *(const short8*)(P + 3145728 + i0);
    short8 o;
    #pragma unroll
    for (int j = 0; j < 8; ++j) {
        float v = bf2f(p0[j]) + bf2f(p1[j]) + bf2f(p2[j]) + bf2f(p3[j]) + bias[col + j];
        o[j] = f2bf(fmaxf(v, 0.f));
    }
    *(short8*)(Hout + i0) = o;
}

// ---------------- softmax + decode + valid ----------------
__global__ void head_epilogue(const float* __restrict__ O,      // [1024][448]
                              const float* __restrict__ props,  // [2][512][4]
                              float* __restrict__ Boxes,        // [2][40960][4]
                              float* __restrict__ Scores,       // [2][40960]
                              unsigned char* __restrict__ Valid) {
    int roi = blockIdx.x;
    int lane = threadIdx.x;  // 64
    const float* o = O + (long)roi * 448;
    float m = -1e30f;
    for (int i = lane; i < 81; i += 64) m = fmaxf(m, o[i]);
    for (int off = 32; off > 0; off >>= 1) m = fmaxf(m, __shfl_xor(m, off));
    float ssum = 0.f;
    for (int i = lane; i < 81; i += 64) ssum += expf(o[i] - m);
    for (int off = 32; off > 0; off >>= 1) ssum += __shfl_xor(ssum, off);
    float inv = 1.0f / ssum;
    int img = roi >> 9, rb = roi & 511;
    float px1 = props[roi * 4 + 0], py1 = props[roi * 4 + 1];
    float px2 = props[roi * 4 + 2], py2 = props[roi * 4 + 3];
    float w = px2 - px1, h = py2 - py1;
    float cx = px1 + 0.5f * w, cy = py1 + 0.5f * h;
    long obase = (long)img * 40960 + (long)rb * 80;
    const float DW = 4.135166556742356f;
    for (int t = lane; t < 80; t += 64) {
        int cls = t + 1;
        float score = expf(o[cls] - m) * inv;
        const float* d = o + 81 + cls * 4;
        float dx = d[0] * 0.1f, dy = d[1] * 0.1f;
        float dw = fminf(d[2] * 0.2f, DW);
        float dh = fminf(d[3] * 0.2f, DW);
        float pcx = dx * w + cx, pcy = dy * h + cy;
        float pw = expf(dw) * w, ph = expf(dh) * h;
        float x1 = pcx - 0.5f * pw, y1 = pcy - 0.5f * ph;
        float x2 = pcx + 0.5f * pw, y2 = pcy + 0.5f * ph;
        x1 = fminf(fmaxf(x1, 0.f), 800.f); y1 = fminf(fmaxf(y1, 0.f), 800.f);
        x2 = fminf(fmaxf(x2, 0.f), 800.f); y2 = fminf(fmaxf(y2, 0.f), 800.f);
        float wv = x2 - x1, hv = y2 - y1;
        long oi = obase + t;
        Boxes[oi * 4 + 0] = x1; Boxes[oi * 4 + 1] = y1;
        Boxes[oi * 4 + 2] = x2; Boxes[oi * 4 + 3] = y2;
        Scores[oi] = score;
        Valid[oi] = (score >= 0.05f && wv >= 1.0f && hv >= 1.0f) ? 1 : 0;
    }
}

// ---------------- order-stable compaction v2 (segment + block prefix) ----------------
__global__ void compact_v2(const float* __restrict__ Boxes, const float* __restrict__ Scores,
                           const unsigned char* __restrict__ Valid,
                           float* __restrict__ CB, float* __restrict__ CS,
                           int* __restrict__ CL, int* __restrict__ CCnt) {
    int img = blockIdx.x;
    int tid = threadIdx.x;  // 256
    const int SEG = 160;    // 40960/256
    const unsigned char* V = Valid + (long)img * 40960;
    int j0 = tid * SEG;
    int c = 0;
    for (int k = 0; k < SEG; ++k) c += V[j0 + k] ? 1 : 0;
    __shared__ int cnt[256];
    cnt[tid] = c;
    __syncthreads();
    for (int d = 1; d < 256; d <<= 1) {
        int v = (tid >= d) ? cnt[tid - d] : 0;
        __syncthreads();
        cnt[tid] += v;
        __syncthreads();
    }
    int pos = cnt[tid] - c;  // exclusive prefix
    const float* B = Boxes + (long)img * 40960 * 4;
    const float* S = Scores + (long)img * 40960;
    float* cb = CB + (long)img * 40960 * 4;
    float* cs = CS + (long)img * 40960;
    int* cl = CL + (long)img * 40960;
    for (int k = 0; k < SEG; ++k) {
        int j = j0 + k;
        if (V[j]) {
            cs[pos] = S[j];
            cb[pos * 4 + 0] = B[j * 4 + 0]; cb[pos * 4 + 1] = B[j * 4 + 1];
            cb[pos * 4 + 2] = B[j * 4 + 2]; cb[pos * 4 + 3] = B[j * 4 + 3];
            cl[pos] = (j % 80) + 1;
            ++pos;
        }
    }
    if (tid == 255) CCnt[img] = cnt[255];
}

// ---------------- greedy NMS + final output (per image) ----------------
__global__ void nms_kernel(const float* __restrict__ CB, const float* __restrict__ CS_in,
                           const int* __restrict__ CL, const int* __restrict__ CCnt,
                           float* __restrict__ out, float* __restrict__ cs_work) {
    int img = blockIdx.x;
    int tid = threadIdx.x;  // 256
    int V = CCnt[img];
    const float* cb = CB + (long)img * 40960 * 4;
    const int* cl = CL + (long)img * 40960;
    const float* csin = CS_in + (long)img * 40960;
    float* sc = cs_work + (long)img * 40960;
    const float NEG = -__builtin_inff();
    for (int j = tid; j < V; j += 256) sc[j] = csin[j];
    for (int i = tid; i < 400; i += 256) out[img * 400 + i] = 0.f;
    if (tid < 100) {
        out[800 + img * 100 + tid] = 0.f;
        out[1000 + img * 100 + tid] = 0.f;
        out[1200 + img * 100 + tid] = 0.f;
    }
    __syncthreads();
    __shared__ float rv[256];
    __shared__ int ri[256];
    __shared__ float selbox[4];
    for (int det = 0; det < 100; ++det) {
        float bv = NEG; int bi = -1;
        for (int j = tid; j < V; j += 256) {
            float s = sc[j];
            if (s > bv) { bv = s; bi = j; }
        }
        rv[tid] = bv; ri[tid] = bi;
        __syncthreads();
        for (int off = 128; off > 0; off >>= 1) {
            if (tid < off) {
                float ov = rv[tid + off]; int oi = ri[tid + off];
                if (ov > rv[tid] ||
                    (ov == rv[tid] && oi != -1 && (ri[tid] == -1 || oi < ri[tid]))) {
                    rv[tid] = ov; ri[tid] = oi;
                }
            }
            __syncthreads();
        }
        float mval = rv[0]; int mi = ri[0];
        if (!(mval > NEG) || mi < 0) break;
        if (tid == 0) {
            out[img * 400 + det * 4 + 0] = cb[mi * 4 + 0];
            out[img * 400 + det * 4 + 1] = cb[mi * 4 + 1];
            out[img * 400 + det * 4 + 2] = cb[mi * 4 + 2];
            out[img * 400 + det * 4 + 3] = cb[mi * 4 + 3];
            out[800 + img * 100 + det] = mval;
            out[1000 + img * 100 + det] = (float)cl[mi];
            out[1200 + img * 100 + det] = 1.0f;
            selbox[0] = cb[mi * 4 + 0]; selbox[1] = cb[mi * 4 + 1];
            selbox[2] = cb[mi * 4 + 2]; selbox[3] = cb[mi * 4 + 3];
            sc[mi] = NEG;
        }
        __syncthreads();
        float bx1 = selbox[0], by1 = selbox[1], bx2 = selbox[2], by2 = selbox[3];
        float a1 = (bx2 - bx1) * (by2 - by1);
        for (int j = tid; j < V; j += 256) {
            float s = sc[j];
            if (s == NEG) continue;
            float x1 = fmaxf(bx1, cb[j * 4 + 0]), y1 = fmaxf(by1, cb[j * 4 + 1]);
            float x2 = fminf(bx2, cb[j * 4 + 2]), y2 = fminf(by2, cb[j * 4 + 3]);
            float iw = fmaxf(x2 - x1, 0.f), ih = fmaxf(y2 - y1, 0.f);
            float inter = iw * ih;
            float a2 = (cb[j * 4 + 2] - cb[j * 4 + 0]) * (cb[j * 4 + 3] - cb[j * 4 + 1]);
            float iou = inter / (a1 + a2 - inter + 1e-9f);
            if (iou > 0.5f) sc[j] = NEG;
        }
        __syncthreads();
    }
}

extern "C" void kernel_launch(void* const* d_in, const int* in_sizes, int n_in,
                              void* d_out, int out_size, void* d_ws, size_t ws_size,
                              hipStream_t stream) {
    const float* features  = (const float*)d_in[0];
    const float* proposals = (const float*)d_in[1];
    const float* W1 = (const float*)d_in[2];
    const float* b1 = (const float*)d_in[3];
    const float* W2 = (const float*)d_in[4];
    const float* b2 = (const float*)d_in[5];
    const float* Wc = (const float*)d_in[6];
    const float* bc = (const float*)d_in[7];
    const float* Wb = (const float*)d_in[8];
    const float* bb = (const float*)d_in[9];

    char* ws = (char*)d_ws;
    // ---- phase-0/1 region (alive through FC1) ----
    short* Xb    = (short*)(ws);                      // [1024][12544] bf16, 25,690,112 B
    short* W1t   = (short*)(ws + 25690112);           // [1024][12544] bf16, 25,690,112 B
    short* featT = (short*)(ws + 51380224);           // [2][2500][256] bf16, 2,560,000 B (dies after roi)
    short* P     = (short*)(ws + 51380224);           // [4][1024][1024] bf16, 8,388,608 B (FC1 partials; reuses featT)
    // ---- phase-2 region (reuses Xb space, all after FC1) ----
    short* H1b   = (short*)(ws);                      // 2,097,152 B
    short* W2t   = (short*)(ws + 2097152);            // 2,097,152 B
    short* Wht   = (short*)(ws + 4194304);            // [448][1024] bf16, 917,504 B
    float* biash = (float*)(ws + 5111808);            // 1,792 B
    short* H2b   = (short*)(ws + 5242880);            // 2,097,152 B
    float* Obuf  = (float*)(ws + 7340032);            // [1024][448] f32, 1,835,008 B
    float* Boxes = (float*)(ws + 9175040);            // 1,310,720 B
    float* Scores= (float*)(ws + 10485760);           // 327,680 B
    unsigned char* Valid = (unsigned char*)(ws + 10813440);  // 81,920 B
    float* CB    = (float*)(ws + 10895360);           // 1,310,720 B
    float* CS    = (float*)(ws + 12206080);           // 327,680 B
    int*   CL    = (int*)(ws + 12533760);             // 327,680 B
    float* CSw   = (float*)(ws + 12861440);           // 327,680 B
    int*   CCnt  = (int*)(ws + 13189120);             // 8 B

    // phase 0: W1 transpose, feature channel-last transpose, roi-align
    transpose_cvt<<<dim3(392, 32), 256, 0, stream>>>(W1, W1t, 12544, 1024, 1024);
    transpose_cvt<<<dim3(8, 79), 256, 0, stream>>>(features, featT, 256, 2500, 2500);
    transpose_cvt<<<dim3(8, 79), 256, 0, stream>>>(features + 640000, featT + 640000, 256, 2500, 2500);
    roi_align_v2<<<1024, 256, 0, stream>>>(featT, proposals, Xb);

    // phase 1: FC1 with split-K x4 (49 k-steps each)
    gemm_bt<0><<<dim3(16, 16, 4), 256, 0, stream>>>(Xb, W1t, nullptr, (void*)P, 1024, 1024, 12544, 49);

    // phase 2: remaining weight transposes into freed region, reduce, FC2, head
    transpose_cvt<<<dim3(32, 32), 256, 0, stream>>>(W2, W2t, 1024, 1024, 1024);
    transpose_cvt<<<dim3(32, 14), 256, 0, stream>>>(Wc, Wht, 1024, 81, 448);
    transpose_cvt<<<dim3(32, 11), 256, 0, stream>>>(Wb, Wht + 81 * 1024, 1024, 324, 324);
    make_bias_h<<<1, 448, 0, stream>>>(bc, bb, biash);
    reduce4_relu<<<512, 256, 0, stream>>>(P, b1, H1b);
    gemm_bt<1><<<dim3(16, 16, 1), 256, 0, stream>>>(H1b, W2t, b2, (void*)H2b, 1024, 1024, 1024, 16);
    gemm_bt<2><<<dim3(7, 16, 1), 256, 0, stream>>>(H2b, Wht, biash, (void*)Obuf, 1024, 448, 1024, 16);

    head_epilogue<<<1024, 64, 0, stream>>>(Obuf, proposals, Boxes, Scores, Valid);
    compact_v2<<<2, 256, 0, stream>>>(Boxes, Scores, Valid, CB, CS, CL, CCnt);
    nms_kernel<<<2, 256, 0, stream>>>(CB, CS, CL, CCnt, (float*)d_out, CSw);
}

// Round 4
// 173.570 us; speedup vs baseline: 2.2906x; 1.0831x over previous
//
#include <hip/hip_runtime.h>
#include <hip/hip_bf16.h>

typedef __attribute__((ext_vector_type(8))) short short8;
typedef __attribute__((ext_vector_type(4))) float f32x4;

__device__ inline short f2bf(float x) {
    union { __hip_bfloat16 b; short s; } u;
    u.b = __float2bfloat16(x);
    return u.s;
}
__device__ inline float bf2f(short s) {
    union { __hip_bfloat16 b; short s; } u;
    u.s = s;
    return __bfloat162float(u.b);
}

#define GLDS16(g, l) __builtin_amdgcn_global_load_lds( \
    (const __attribute__((address_space(1))) void*)(g), \
    (__attribute__((address_space(3))) void*)(l), 16, 0, 0)

// ---------------- transpose + f32->bf16 convert (batched over z) ----------------
// in [R][C] f32 -> out [n][R] bf16 for n in [0,Cp); cols >= C read as 0.
__global__ void transpose_cvt(const float* __restrict__ in, short* __restrict__ out,
                              int R, int C, int Cp, long istride, long ostride) {
    in += blockIdx.z * istride;
    out += blockIdx.z * ostride;
    __shared__ float tile[32][33];
    int r0 = blockIdx.x * 32;
    int c0 = blockIdx.y * 32;
    int tr = threadIdx.x >> 5;
    int tc = threadIdx.x & 31;
    #pragma unroll
    for (int i = 0; i < 4; ++i) {
        int r = r0 + tr + i * 8;
        int c = c0 + tc;
        float v = 0.f;
        if (c < C) v = in[(long)r * C + c];
        tile[tr + i * 8][tc] = v;
    }
    __syncthreads();
    #pragma unroll
    for (int i = 0; i < 4; ++i) {
        int n = c0 + tr + i * 8;
        int k = r0 + tc;
        if (n < Cp) out[(long)n * R + k] = f2bf(tile[tc][tr + i * 8]);
    }
}

// ---------------- combined W2/Wc/Wb transpose (all have 1024 rows) ----------------
__global__ void transpose_w3(const float* __restrict__ W2, const float* __restrict__ Wc,
                             const float* __restrict__ Wb,
                             short* __restrict__ W2t, short* __restrict__ Wht) {
    int z = blockIdx.z;
    const float* in;
    short* out;
    int C, ylim;
    if (z == 0)      { in = W2; out = W2t;             C = 1024; ylim = 32; }
    else if (z == 1) { in = Wc; out = Wht;             C = 81;   ylim = 3;  }
    else             { in = Wb; out = Wht + 81 * 1024; C = 324;  ylim = 11; }
    if ((int)blockIdx.y >= ylim) return;
    __shared__ float tile[32][33];
    int r0 = blockIdx.x * 32;
    int c0 = blockIdx.y * 32;
    int tr = threadIdx.x >> 5;
    int tc = threadIdx.x & 31;
    #pragma unroll
    for (int i = 0; i < 4; ++i) {
        int r = r0 + tr + i * 8;
        int c = c0 + tc;
        float v = 0.f;
        if (c < C) v = in[(long)r * C + c];   // FIX: row stride is C (81/324/1024), not 1024
        tile[tr + i * 8][tc] = v;
    }
    __syncthreads();
    #pragma unroll
    for (int i = 0; i < 4; ++i) {
        int n = c0 + tr + i * 8;
        int k = r0 + tc;
        if (n < C) out[(long)n * 1024 + k] = f2bf(tile[tc][tr + i * 8]);
    }
}

// ---------------- ROI-align: channel-last bf16 features ----------------
__global__ __launch_bounds__(256) void roi_align_v2(const short* __restrict__ featT,
                                                    const float* __restrict__ props,
                                                    short* __restrict__ Xb) {
    int roi = blockIdx.x;
    int img = roi >> 9;
    __shared__ int   sbase[196];
    __shared__ int   sdx[196];
    __shared__ int   sdy[196];
    __shared__ float w00s[196], w01s[196], w10s[196], w11s[196];
    __shared__ float pbox[4];
    __shared__ short outb[49 * 260];
    int tid = threadIdx.x;
    if (tid < 4) pbox[tid] = props[roi * 4 + tid];
    __syncthreads();
    if (tid < 196) {
        float x1 = pbox[0] * 0.0625f, y1 = pbox[1] * 0.0625f;
        float x2 = pbox[2] * 0.0625f, y2 = pbox[3] * 0.0625f;
        float rw = fmaxf(x2 - x1, 1.0f), rh = fmaxf(y2 - y1, 1.0f);
        int p = tid >> 2, q = tid & 3;
        int py = p / 7, px = p % 7;
        int sy = q >> 1, sx = q & 1;
        int gy = py * 2 + sy, gx = px * 2 + sx;
        float gyv = ((float)gy + 0.5f) * 0.5f;
        float gxv = ((float)gx + 0.5f) * 0.5f;
        float ys = y1 + gyv * (rh * (1.0f / 7.0f));
        float xs = x1 + gxv * (rw * (1.0f / 7.0f));
        ys = fminf(fmaxf(ys, 0.0f), 49.0f);
        xs = fminf(fmaxf(xs, 0.0f), 49.0f);
        float y0f = floorf(ys), x0f = floorf(xs);
        int y0 = (int)y0f, x0 = (int)x0f;
        int y1i = min(y0 + 1, 49), x1i = min(x0 + 1, 49);
        float ly = ys - y0f, lx = xs - x0f;
        float hy = 1.f - ly, hx = 1.f - lx;
        sbase[tid] = (y0 * 50 + x0) * 256;
        sdx[tid] = (x1i - x0) * 256;
        sdy[tid] = (y1i - y0) * 50 * 256;
        w00s[tid] = hy * hx; w01s[tid] = hy * lx;
        w10s[tid] = ly * hx; w11s[tid] = ly * lx;
    }
    __syncthreads();
    const short* fb = featT + (long)img * 2500 * 256 + tid;
    #pragma unroll 1
    for (int p = 0; p < 49; ++p) {
        float acc = 0.f;
        #pragma unroll
        for (int q = 0; q < 4; ++q) {
            int s = p * 4 + q;
            int b = sbase[s], dx = sdx[s], dy = sdy[s];
            float f00 = bf2f(fb[b]);
            float f01 = bf2f(fb[b + dx]);
            float f10 = bf2f(fb[b + dy]);
            float f11 = bf2f(fb[b + dy + dx]);
            acc += w00s[s] * f00 + w01s[s] * f01 + w10s[s] * f10 + w11s[s] * f11;
        }
        outb[p * 260 + tid] = f2bf(acc * 0.25f);
    }
    __syncthreads();
    int c = tid / 49, r = tid % 49;
    short* xrow = Xb + (long)roi * 12544;
    #pragma unroll 1
    for (int i = 0; i < 49; ++i) {
        int e = tid + i * 256;
        xrow[e] = outb[r * 260 + c];
        c += 5; r += 11;
        if (r >= 49) { r -= 49; c += 1; }
    }
}

// ---------------- 128x128 MFMA GEMM, glds staging + XOR swizzle + dbuf ----------------
// C = A[M,K] @ Bt[N,K]^T
// MODE 0: partial -> bf16 at Cout + z*M*N (no bias)
// MODE 1: bias+relu -> bf16
// MODE 2: (bc|bb|0) bias -> f32, store only col < Ncap
template <int MODE>
__global__ __launch_bounds__(256) void gemm128(const short* __restrict__ A,
                                               const short* __restrict__ Bt,
                                               const float* __restrict__ bias,
                                               const float* __restrict__ bias2,
                                               void* __restrict__ Cout,
                                               int M, int N, int K, int ksteps, int Ncap) {
    __shared__ short As[2][128 * 64];
    __shared__ short Bs[2][128 * 64];
    int bx_ = blockIdx.x, by_ = blockIdx.y, bz_ = blockIdx.z;
    if (gridDim.z == 4 && gridDim.x == 8 && gridDim.y == 8) {
        // XCD-chunked remap: each XCD gets one z-halfplane (L2 locality)
        int lin = bx_ + (by_ << 3) + (bz_ << 6);
        int xcd = lin & 7, i = lin >> 3;
        bz_ = xcd >> 1;
        by_ = ((xcd & 1) << 2) + (i >> 3);
        bx_ = i & 7;
    }
    int m0 = by_ * 128, n0 = bx_ * 128;
    long kbeg = (long)bz_ * ksteps * 64;
    int tid = threadIdx.x;
    int w = tid >> 6, lane = tid & 63;
    int wr = w >> 1, wc = w & 1;
    int lr = lane & 15, lk = lane >> 4;
    // staging: LDS linear [row][64k], source pre-swizzled so ds_read can XOR
    int srow = tid >> 3;
    int sbx = ((tid & 7) ^ (srow & 7)) << 4;
    const char* Ag = (const char*)A + ((long)(m0 + srow) * K + kbeg) * 2 + sbx;
    const char* Bg = (const char*)Bt + ((long)(n0 + srow) * K + kbeg) * 2 + sbx;
    const long rstep = (long)K * 64;  // 32 rows * K * 2B
    char* As0 = (char*)&As[0][0];
    char* Bs0 = (char*)&Bs[0][0];
    int wofs = w << 10;
    int sw = (lr & 7) << 4;
    f32x4 acc[4][4] = {};

    #pragma unroll
    for (int i = 0; i < 4; ++i) {
        GLDS16(Ag + i * rstep, As0 + wofs + i * 4096);
        GLDS16(Bg + i * rstep, Bs0 + wofs + i * 4096);
    }
    __syncthreads();
    int cur = 0;
    for (int t = 0; t < ksteps; ++t) {
        if (t + 1 < ksteps) {
            const char* a = Ag + (long)(t + 1) * 128;
            const char* b = Bg + (long)(t + 1) * 128;
            char* ad = As0 + ((cur ^ 1) << 14) + wofs;
            char* bd = Bs0 + ((cur ^ 1) << 14) + wofs;
            #pragma unroll
            for (int i = 0; i < 4; ++i) {
                GLDS16(a + i * rstep, ad + i * 4096);
                GLDS16(b + i * rstep, bd + i * 4096);
            }
        }
        const char* as = As0 + (cur << 14);
        const char* bs = Bs0 + (cur << 14);
        #pragma unroll
        for (int kk = 0; kk < 2; ++kk) {
            short8 av[4], bv[4];
            #pragma unroll
            for (int f = 0; f < 4; ++f) {
                av[f] = *(const short8*)(as + (wr * 64 + f * 16 + lr) * 128 + ((kk * 64 + lk * 16) ^ sw));
                bv[f] = *(const short8*)(bs + (wc * 64 + f * 16 + lr) * 128 + ((kk * 64 + lk * 16) ^ sw));
            }
            #pragma unroll
            for (int fm = 0; fm < 4; ++fm)
                #pragma unroll
                for (int fn = 0; fn < 4; ++fn)
                    acc[fm][fn] = __builtin_amdgcn_mfma_f32_16x16x32_bf16(av[fm], bv[fn], acc[fm][fn], 0, 0, 0);
        }
        __syncthreads();
        cur ^= 1;
    }
    #pragma unroll
    for (int fm = 0; fm < 4; ++fm) {
        #pragma unroll
        for (int fn = 0; fn < 4; ++fn) {
            int col = n0 + wc * 64 + fn * 16 + lr;
            float bv = 0.f;
            if (MODE == 1) bv = bias[col];
            if (MODE == 2) bv = (col < 81) ? bias[col] : (col < 405 ? bias2[col - 81] : 0.f);
            #pragma unroll
            for (int j = 0; j < 4; ++j) {
                int row = m0 + wr * 64 + fm * 16 + lk * 4 + j;
                float v = acc[fm][fn][j];
                if (MODE == 0) {
                    ((short*)Cout)[(long)bz_ * M * N + (long)row * N + col] = f2bf(v);
                } else if (MODE == 1) {
                    ((short*)Cout)[(long)row * N + col] = f2bf(fmaxf(v + bv, 0.f));
                } else {
                    if (col < Ncap) ((float*)Cout)[(long)row * N + col] = v + bv;
                }
            }
        }
    }
}

// ---------------- split-K reduce: H1 = relu(sum_s P[s] + b1) -> bf16 ----------------
__global__ void reduce4_relu(const short* __restrict__ P, const float* __restrict__ bias,
                             short* __restrict__ Hout) {
    long i0 = ((long)blockIdx.x * 256 + threadIdx.x) * 8;
    int col = (int)(i0 & 1023);
    short8 p0 = *(const short8*)(P + i0);
    short8 p1 = *(const short8*)(P + 1048576 + i0);
    short8 p2 = *(const short8*)(P + 2097152 + i0);
    short8 p3 = *(const short8*)(P + 3145728 + i0);
    short8 o;
    #pragma unroll
    for (int j = 0; j < 8; ++j) {
        float v = bf2f(p0[j]) + bf2f(p1[j]) + bf2f(p2[j]) + bf2f(p3[j]) + bias[col + j];
        o[j] = f2bf(fmaxf(v, 0.f));
    }
    *(short8*)(Hout + i0) = o;
}

// ---------------- softmax + decode + valid ----------------
__global__ void head_epilogue(const float* __restrict__ O,      // [1024][448]
                              const float* __restrict__ props,
                              float* __restrict__ Boxes,
                              float* __restrict__ Scores,
                              unsigned char* __restrict__ Valid) {
    int roi = blockIdx.x;
    int lane = threadIdx.x;  // 64
    const float* o = O + (long)roi * 448;
    float m = -1e30f;
    for (int i = lane; i < 81; i += 64) m = fmaxf(m, o[i]);
    for (int off = 32; off > 0; off >>= 1) m = fmaxf(m, __shfl_xor(m, off));
    float ssum = 0.f;
    for (int i = lane; i < 81; i += 64) ssum += expf(o[i] - m);
    for (int off = 32; off > 0; off >>= 1) ssum += __shfl_xor(ssum, off);
    float inv = 1.0f / ssum;
    int img = roi >> 9, rb = roi & 511;
    float px1 = props[roi * 4 + 0], py1 = props[roi * 4 + 1];
    float px2 = props[roi * 4 + 2], py2 = props[roi * 4 + 3];
    float w = px2 - px1, h = py2 - py1;
    float cx = px1 + 0.5f * w, cy = py1 + 0.5f * h;
    long obase = (long)img * 40960 + (long)rb * 80;
    const float DW = 4.135166556742356f;
    for (int t = lane; t < 80; t += 64) {
        int cls = t + 1;
        float score = expf(o[cls] - m) * inv;
        const float* d = o + 81 + cls * 4;
        float dx = d[0] * 0.1f, dy = d[1] * 0.1f;
        float dw = fminf(d[2] * 0.2f, DW);
        float dh = fminf(d[3] * 0.2f, DW);
        float pcx = dx * w + cx, pcy = dy * h + cy;
        float pw = expf(dw) * w, ph = expf(dh) * h;
        float x1 = pcx - 0.5f * pw, y1 = pcy - 0.5f * ph;
        float x2 = pcx + 0.5f * pw, y2 = pcy + 0.5f * ph;
        x1 = fminf(fmaxf(x1, 0.f), 800.f); y1 = fminf(fmaxf(y1, 0.f), 800.f);
        x2 = fminf(fmaxf(x2, 0.f), 800.f); y2 = fminf(fmaxf(y2, 0.f), 800.f);
        float wv = x2 - x1, hv = y2 - y1;
        long oi = obase + t;
        Boxes[oi * 4 + 0] = x1; Boxes[oi * 4 + 1] = y1;
        Boxes[oi * 4 + 2] = x2; Boxes[oi * 4 + 3] = y2;
        Scores[oi] = score;
        Valid[oi] = (score >= 0.05f && wv >= 1.0f && hv >= 1.0f) ? 1 : 0;
    }
}

// ---------------- fused compaction + greedy NMS (one block per image) ----------------
__global__ void nms_fused(const float* __restrict__ Boxes, const float* __restrict__ Scores,
                          const unsigned char* __restrict__ Valid,
                          float* __restrict__ CB, int* __restrict__ CL,
                          float* __restrict__ CSw, float* __restrict__ out) {
    int img = blockIdx.x;
    int tid = threadIdx.x;  // 256
    const int SEG = 160;    // 40960/256
    const unsigned char* V = Valid + (long)img * 40960;
    int j0 = tid * SEG;
    int c = 0;
    for (int k = 0; k < SEG; ++k) c += V[j0 + k] ? 1 : 0;
    __shared__ int cnt[256];
    cnt[tid] = c;
    __syncthreads();
    for (int d = 1; d < 256; d <<= 1) {
        int v = (tid >= d) ? cnt[tid - d] : 0;
        __syncthreads();
        cnt[tid] += v;
        __syncthreads();
    }
    int pos = cnt[tid] - c;
    const float* B = Boxes + (long)img * 40960 * 4;
    const float* S = Scores + (long)img * 40960;
    float* cb = CB + (long)img * 40960 * 4;
    float* sc = CSw + (long)img * 40960;
    int* cl = CL + (long)img * 40960;
    for (int k = 0; k < SEG; ++k) {
        int j = j0 + k;
        if (V[j]) {
            sc[pos] = S[j];
            cb[pos * 4 + 0] = B[j * 4 + 0]; cb[pos * 4 + 1] = B[j * 4 + 1];
            cb[pos * 4 + 2] = B[j * 4 + 2]; cb[pos * 4 + 3] = B[j * 4 + 3];
            cl[pos] = (j % 80) + 1;
            ++pos;
        }
    }
    int Vn = cnt[255];
    for (int i = tid; i < 400; i += 256) out[img * 400 + i] = 0.f;
    if (tid < 100) {
        out[800 + img * 100 + tid] = 0.f;
        out[1000 + img * 100 + tid] = 0.f;
        out[1200 + img * 100 + tid] = 0.f;
    }
    __syncthreads();
    __shared__ float rv[256];
    __shared__ int ri[256];
    __shared__ float selbox[4];
    const float NEG = -__builtin_inff();
    for (int det = 0; det < 100; ++det) {
        float bv = NEG; int bi = -1;
        for (int j = tid; j < Vn; j += 256) {
            float s = sc[j];
            if (s > bv) { bv = s; bi = j; }
        }
        rv[tid] = bv; ri[tid] = bi;
        __syncthreads();
        for (int off = 128; off > 0; off >>= 1) {
            if (tid < off) {
                float ov = rv[tid + off]; int oi = ri[tid + off];
                if (ov > rv[tid] ||
                    (ov == rv[tid] && oi != -1 && (ri[tid] == -1 || oi < ri[tid]))) {
                    rv[tid] = ov; ri[tid] = oi;
                }
            }
            __syncthreads();
        }
        float mval = rv[0]; int mi = ri[0];
        if (!(mval > NEG) || mi < 0) break;
        if (tid == 0) {
            out[img * 400 + det * 4 + 0] = cb[mi * 4 + 0];
            out[img * 400 + det * 4 + 1] = cb[mi * 4 + 1];
            out[img * 400 + det * 4 + 2] = cb[mi * 4 + 2];
            out[img * 400 + det * 4 + 3] = cb[mi * 4 + 3];
            out[800 + img * 100 + det] = mval;
            out[1000 + img * 100 + det] = (float)cl[mi];
            out[1200 + img * 100 + det] = 1.0f;
            selbox[0] = cb[mi * 4 + 0]; selbox[1] = cb[mi * 4 + 1];
            selbox[2] = cb[mi * 4 + 2]; selbox[3] = cb[mi * 4 + 3];
            sc[mi] = NEG;
        }
        __syncthreads();
        float bx1 = selbox[0], by1 = selbox[1], bx2 = selbox[2], by2 = selbox[3];
        float a1 = (bx2 - bx1) * (by2 - by1);
        for (int j = tid; j < Vn; j += 256) {
            float s = sc[j];
            if (s == NEG) continue;
            float x1 = fmaxf(bx1, cb[j * 4 + 0]), y1 = fmaxf(by1, cb[j * 4 + 1]);
            float x2 = fminf(bx2, cb[j * 4 + 2]), y2 = fminf(by2, cb[j * 4 + 3]);
            float iw = fmaxf(x2 - x1, 0.f), ih = fmaxf(y2 - y1, 0.f);
            float inter = iw * ih;
            float a2 = (cb[j * 4 + 2] - cb[j * 4 + 0]) * (cb[j * 4 + 3] - cb[j * 4 + 1]);
            float iou = inter / (a1 + a2 - inter + 1e-9f);
            if (iou > 0.5f) sc[j] = NEG;
        }
        __syncthreads();
    }
}

extern "C" void kernel_launch(void* const* d_in, const int* in_sizes, int n_in,
                              void* d_out, int out_size, void* d_ws, size_t ws_size,
                              hipStream_t stream) {
    const float* features  = (const float*)d_in[0];
    const float* proposals = (const float*)d_in[1];
    const float* W1 = (const float*)d_in[2];
    const float* b1 = (const float*)d_in[3];
    const float* W2 = (const float*)d_in[4];
    const float* b2 = (const float*)d_in[5];
    const float* Wc = (const float*)d_in[6];
    const float* bc = (const float*)d_in[7];
    const float* Wb = (const float*)d_in[8];
    const float* bb = (const float*)d_in[9];

    char* ws = (char*)d_ws;
    // phase A
    short* Xb    = (short*)(ws);                      // 25,690,112 B
    short* W1t   = (short*)(ws + 25690112);           // 25,690,112 B
    short* featT = (short*)(ws + 51380224);           // 2,560,000 B (dies before P)
    short* P     = (short*)(ws + 51380224);           // [4][1024][1024] bf16, 8,388,608 B
    // phase B (inside ex-Xb region, all used after FC1)
    short* H1b   = (short*)(ws);                      // 2 MB
    short* W2t   = (short*)(ws + 2097152);            // 2 MB
    short* Wht   = (short*)(ws + 4194304);            // [512][1024] bf16, 1 MB
    short* H2b   = (short*)(ws + 5242880);            // 2 MB
    float* Obuf  = (float*)(ws + 7340032);            // [1024][448] f32
    float* Boxes = (float*)(ws + 9175040);
    float* Scores= (float*)(ws + 10485760);
    unsigned char* Valid = (unsigned char*)(ws + 10813440);
    float* CB    = (float*)(ws + 10895360);
    int*   CL    = (int*)(ws + 12206080);
    float* CSw   = (float*)(ws + 12533760);

    transpose_cvt<<<dim3(392, 32, 1), 256, 0, stream>>>(W1, W1t, 12544, 1024, 1024, 0, 0);
    transpose_cvt<<<dim3(8, 79, 2), 256, 0, stream>>>(features, featT, 256, 2500, 2500, 640000, 640000);
    roi_align_v2<<<1024, 256, 0, stream>>>(featT, proposals, Xb);

    gemm128<0><<<dim3(8, 8, 4), 256, 0, stream>>>(Xb, W1t, nullptr, nullptr, (void*)P,
                                                  1024, 1024, 12544, 49, 1024);

    transpose_w3<<<dim3(32, 32, 3), 256, 0, stream>>>(W2, Wc, Wb, W2t, Wht);
    reduce4_relu<<<512, 256, 0, stream>>>(P, b1, H1b);
    gemm128<1><<<dim3(8, 8, 1), 256, 0, stream>>>(H1b, W2t, b2, nullptr, (void*)H2b,
                                                  1024, 1024, 1024, 16, 1024);
    gemm128<2><<<dim3(4, 8, 1), 256, 0, stream>>>(H2b, Wht, bc, bb, (void*)Obuf,
                                                  1024, 448, 1024, 16, 448);

    head_epilogue<<<1024, 64, 0, stream>>>(Obuf, proposals, Boxes, Scores, Valid);
    nms_fused<<<2, 256, 0, stream>>>(Boxes, Scores, Valid, CB, CL, CSw, (float*)d_out);
}

// Round 5
// 124.225 us; speedup vs baseline: 3.2005x; 1.3972x over previous
//
#include <hip/hip_runtime.h>
#include <hip/hip_bf16.h>

typedef __attribute__((ext_vector_type(8))) short short8;
typedef __attribute__((ext_vector_type(4))) float f32x4;

__device__ inline short f2bf(float x) {
    union { __hip_bfloat16 b; short s; } u;
    u.b = __float2bfloat16(x);
    return u.s;
}
__device__ inline float bf2f(short s) {
    union { __hip_bfloat16 b; short s; } u;
    u.s = s;
    return __bfloat162float(u.b);
}

#define GLDS16(g, l) __builtin_amdgcn_global_load_lds( \
    (const __attribute__((address_space(1))) void*)(g), \
    (__attribute__((address_space(3))) void*)(l), 16, 0, 0)

// ---------------- merged transpose + f32->bf16 convert (all weights + features) ----
// jobs by linear block id:
//  [0,12544)      W1   [12544][1024] -> W1t[1024][12544]
//  [12544,13808)  feat [256][2500] x2 -> featT[2500][256] (per image)
//  [13808,14832)  W2   [1024][1024] -> W2t
//  [14832,14928)  Wc   [1024][81]   -> Wht[0..81)
//  [14928,15280)  Wb   [1024][324]  -> Wht[81..405)
__global__ void transpose_all(const float* __restrict__ W1, const float* __restrict__ features,
                              const float* __restrict__ W2, const float* __restrict__ Wc,
                              const float* __restrict__ Wb,
                              short* __restrict__ W1t, short* __restrict__ featT,
                              short* __restrict__ W2t, short* __restrict__ Wht) {
    int id = blockIdx.x;
    const float* in;
    short* out;
    int R, C, r0, c0;
    if (id < 12544) {
        in = W1; out = W1t; R = 12544; C = 1024;
        r0 = (id % 392) * 32; c0 = (id / 392) * 32;
    } else if (id < 13808) {
        int f = id - 12544;
        int img = f / 632, g = f % 632;
        in = features + (long)img * 640000;
        out = featT + (long)img * 640000;
        R = 256; C = 2500;
        r0 = (g % 8) * 32; c0 = (g / 8) * 32;
    } else if (id < 14832) {
        int g = id - 13808;
        in = W2; out = W2t; R = 1024; C = 1024;
        r0 = (g % 32) * 32; c0 = (g / 32) * 32;
    } else if (id < 14928) {
        int g = id - 14832;
        in = Wc; out = Wht; R = 1024; C = 81;
        r0 = (g % 32) * 32; c0 = (g / 32) * 32;
    } else {
        int g = id - 14928;
        in = Wb; out = Wht + 81 * 1024; R = 1024; C = 324;
        r0 = (g % 32) * 32; c0 = (g / 32) * 32;
    }
    __shared__ float tile[32][33];
    int tr = threadIdx.x >> 5;
    int tc = threadIdx.x & 31;
    #pragma unroll
    for (int i = 0; i < 4; ++i) {
        int r = r0 + tr + i * 8;
        int c = c0 + tc;
        float v = 0.f;
        if (c < C) v = in[(long)r * C + c];
        tile[tr + i * 8][tc] = v;
    }
    __syncthreads();
    #pragma unroll
    for (int i = 0; i < 4; ++i) {
        int n = c0 + tr + i * 8;
        int k = r0 + tc;
        if (n < C) out[(long)n * R + k] = f2bf(tile[tc][tr + i * 8]);
    }
}

// ---------------- ROI-align v3: 16B vector loads, wave-half corner split ----------
// featT [2][2500][256] bf16. Lane covers 8 channels; lanes 0-31 / 32-63 take the
// two corners of each load-pair; per-sample tables read once per 256 channels.
__global__ __launch_bounds__(256) void roi_align_v3(const short* __restrict__ featT,
                                                    const float* __restrict__ props,
                                                    short* __restrict__ Xb) {
    int roi = blockIdx.x;
    int img = roi >> 9;
    __shared__ unsigned int soffB[784];  // byte offset of corner-row, [s*4+corner]
    __shared__ float swB[784];           // weight (incl. /4 subsample mean)
    __shared__ float pbox[4];
    __shared__ short outb[49 * 264];     // [p][ch] staging
    int tid = threadIdx.x;
    if (tid < 4) pbox[tid] = props[roi * 4 + tid];
    __syncthreads();
    if (tid < 196) {
        float x1 = pbox[0] * 0.0625f, y1 = pbox[1] * 0.0625f;
        float x2 = pbox[2] * 0.0625f, y2 = pbox[3] * 0.0625f;
        float rw = fmaxf(x2 - x1, 1.0f), rh = fmaxf(y2 - y1, 1.0f);
        int p = tid >> 2, q = tid & 3;
        int py = p / 7, px = p % 7;
        int sy = q >> 1, sx = q & 1;
        int gy = py * 2 + sy, gx = px * 2 + sx;
        float gyv = ((float)gy + 0.5f) * 0.5f;
        float gxv = ((float)gx + 0.5f) * 0.5f;
        float ys = y1 + gyv * (rh * (1.0f / 7.0f));
        float xs = x1 + gxv * (rw * (1.0f / 7.0f));
        ys = fminf(fmaxf(ys, 0.0f), 49.0f);
        xs = fminf(fmaxf(xs, 0.0f), 49.0f);
        float y0f = floorf(ys), x0f = floorf(xs);
        int y0 = (int)y0f, x0 = (int)x0f;
        int y1i = min(y0 + 1, 49), x1i = min(x0 + 1, 49);
        float ly = ys - y0f, lx = xs - x0f;
        float hy = 1.f - ly, hx = 1.f - lx;
        int b00 = (y0 * 50 + x0) << 9;       // row bytes = 256ch * 2B = 512
        int ddx = (x1i - x0) << 9;
        int ddy = (y1i - y0) * 25600;        // 50*512
        int t4 = tid << 2;
        soffB[t4 + 0] = b00;             swB[t4 + 0] = hy * hx * 0.25f;
        soffB[t4 + 1] = b00 + ddx;       swB[t4 + 1] = hy * lx * 0.25f;
        soffB[t4 + 2] = b00 + ddy;       swB[t4 + 2] = ly * hx * 0.25f;
        soffB[t4 + 3] = b00 + ddy + ddx; swB[t4 + 3] = ly * lx * 0.25f;
    }
    __syncthreads();
    int w = tid >> 6, l = tid & 63;
    int half = l >> 5, ch16 = l & 31;
    const char* fbase = (const char*)featT + (long)img * 1280000 + (ch16 << 4);
    for (int p = w; p < 49; p += 4) {
        float acc[8] = {};
        #pragma unroll
        for (int ld = 0; ld < 8; ++ld) {
            int idx = (p << 4) + (ld << 1) + half;   // = (sample)*4 + corner
            unsigned int off = soffB[idx];
            float wgt = swB[idx];
            short8 v = *(const short8*)(fbase + off);
            union { short8 s; unsigned int u[4]; } uv;
            uv.s = v;
            #pragma unroll
            for (int k2 = 0; k2 < 4; ++k2) {
                unsigned int u = uv.u[k2];
                float flo = __uint_as_float(u << 16);
                float fhi = __uint_as_float(u & 0xffff0000u);
                acc[k2 * 2]     += wgt * flo;
                acc[k2 * 2 + 1] += wgt * fhi;
            }
        }
        short8 o;
        #pragma unroll
        for (int j = 0; j < 8; ++j) {
            float t = acc[j] + __shfl_xor(acc[j], 32);
            o[j] = f2bf(t);
        }
        if (half == 0) *(short8*)&outb[p * 264 + (ch16 << 3)] = o;
    }
    __syncthreads();
    // coalesced writeout: element e = c*49 + p
    int c = tid / 49, r = tid % 49;
    short* xrow = Xb + (long)roi * 12544;
    #pragma unroll 1
    for (int i = 0; i < 49; ++i) {
        xrow[tid + i * 256] = outb[r * 264 + c];
        c += 5; r += 11;
        if (r >= 49) { r -= 49; c += 1; }
    }
}

// ---------------- 128x128 MFMA GEMM, glds staging + XOR swizzle + dbuf ----------------
// C = A[M,K] @ Bt[N,K]^T
// MODE 0: partial -> bf16 at Cout + z*M*N (no bias)
// MODE 1: bias+relu -> bf16
// MODE 2: (bc|bb|0) bias -> f32, store only col < Ncap
template <int MODE>
__global__ __launch_bounds__(256) void gemm128(const short* __restrict__ A,
                                               const short* __restrict__ Bt,
                                               const float* __restrict__ bias,
                                               const float* __restrict__ bias2,
                                               void* __restrict__ Cout,
                                               int M, int N, int K, int ksteps, int Ncap) {
    __shared__ short As[2][128 * 64];
    __shared__ short Bs[2][128 * 64];
    int bx_ = blockIdx.x, by_ = blockIdx.y, bz_ = blockIdx.z;
    if (gridDim.z == 4 && gridDim.x == 8 && gridDim.y == 8) {
        int lin = bx_ + (by_ << 3) + (bz_ << 6);
        int xcd = lin & 7, i = lin >> 3;
        bz_ = xcd >> 1;
        by_ = ((xcd & 1) << 2) + (i >> 3);
        bx_ = i & 7;
    }
    int m0 = by_ * 128, n0 = bx_ * 128;
    long kbeg = (long)bz_ * ksteps * 64;
    int tid = threadIdx.x;
    int w = tid >> 6, lane = tid & 63;
    int wr = w >> 1, wc = w & 1;
    int lr = lane & 15, lk = lane >> 4;
    int srow = tid >> 3;
    int sbx = ((tid & 7) ^ (srow & 7)) << 4;
    const char* Ag = (const char*)A + ((long)(m0 + srow) * K + kbeg) * 2 + sbx;
    const char* Bg = (const char*)Bt + ((long)(n0 + srow) * K + kbeg) * 2 + sbx;
    const long rstep = (long)K * 64;
    char* As0 = (char*)&As[0][0];
    char* Bs0 = (char*)&Bs[0][0];
    int wofs = w << 10;
    int sw = (lr & 7) << 4;
    f32x4 acc[4][4] = {};

    #pragma unroll
    for (int i = 0; i < 4; ++i) {
        GLDS16(Ag + i * rstep, As0 + wofs + i * 4096);
        GLDS16(Bg + i * rstep, Bs0 + wofs + i * 4096);
    }
    __syncthreads();
    int cur = 0;
    for (int t = 0; t < ksteps; ++t) {
        if (t + 1 < ksteps) {
            const char* a = Ag + (long)(t + 1) * 128;
            const char* b = Bg + (long)(t + 1) * 128;
            char* ad = As0 + ((cur ^ 1) << 14) + wofs;
            char* bd = Bs0 + ((cur ^ 1) << 14) + wofs;
            #pragma unroll
            for (int i = 0; i < 4; ++i) {
                GLDS16(a + i * rstep, ad + i * 4096);
                GLDS16(b + i * rstep, bd + i * 4096);
            }
        }
        const char* as = As0 + (cur << 14);
        const char* bs = Bs0 + (cur << 14);
        #pragma unroll
        for (int kk = 0; kk < 2; ++kk) {
            short8 av[4], bv[4];
            #pragma unroll
            for (int f = 0; f < 4; ++f) {
                av[f] = *(const short8*)(as + (wr * 64 + f * 16 + lr) * 128 + ((kk * 64 + lk * 16) ^ sw));
                bv[f] = *(const short8*)(bs + (wc * 64 + f * 16 + lr) * 128 + ((kk * 64 + lk * 16) ^ sw));
            }
            #pragma unroll
            for (int fm = 0; fm < 4; ++fm)
                #pragma unroll
                for (int fn = 0; fn < 4; ++fn)
                    acc[fm][fn] = __builtin_amdgcn_mfma_f32_16x16x32_bf16(av[fm], bv[fn], acc[fm][fn], 0, 0, 0);
        }
        __syncthreads();
        cur ^= 1;
    }
    #pragma unroll
    for (int fm = 0; fm < 4; ++fm) {
        #pragma unroll
        for (int fn = 0; fn < 4; ++fn) {
            int col = n0 + wc * 64 + fn * 16 + lr;
            float bv = 0.f;
            if (MODE == 1) bv = bias[col];
            if (MODE == 2) bv = (col < 81) ? bias[col] : (col < 405 ? bias2[col - 81] : 0.f);
            #pragma unroll
            for (int j = 0; j < 4; ++j) {
                int row = m0 + wr * 64 + fm * 16 + lk * 4 + j;
                float v = acc[fm][fn][j];
                if (MODE == 0) {
                    ((short*)Cout)[(long)bz_ * M * N + (long)row * N + col] = f2bf(v);
                } else if (MODE == 1) {
                    ((short*)Cout)[(long)row * N + col] = f2bf(fmaxf(v + bv, 0.f));
                } else {
                    if (col < Ncap) ((float*)Cout)[(long)row * N + col] = v + bv;
                }
            }
        }
    }
}

// ---------------- split-K reduce: H1 = relu(sum_s P[s] + b1) -> bf16 ----------------
__global__ void reduce4_relu(const short* __restrict__ P, const float* __restrict__ bias,
                             short* __restrict__ Hout) {
    long i0 = ((long)blockIdx.x * 256 + threadIdx.x) * 8;
    int col = (int)(i0 & 1023);
    short8 p0 = *(const short8*)(P + i0);
    short8 p1 = *(const short8*)(P + 1048576 + i0);
    short8 p2 = *(const short8*)(P + 2097152 + i0);
    short8 p3 = *(const short8*)(P + 3145728 + i0);
    short8 o;
    #pragma unroll
    for (int j = 0; j < 8; ++j) {
        float v = bf2f(p0[j]) + bf2f(p1[j]) + bf2f(p2[j]) + bf2f(p3[j]) + bias[col + j];
        o[j] = f2bf(fmaxf(v, 0.f));
    }
    *(short8*)(Hout + i0) = o;
}

// ---------------- softmax + decode + valid ----------------
__global__ void head_epilogue(const float* __restrict__ O,      // [1024][448]
                              const float* __restrict__ props,
                              float* __restrict__ Boxes,
                              float* __restrict__ Scores,
                              unsigned char* __restrict__ Valid) {
    int roi = blockIdx.x;
    int lane = threadIdx.x;  // 64
    const float* o = O + (long)roi * 448;
    float m = -1e30f;
    for (int i = lane; i < 81; i += 64) m = fmaxf(m, o[i]);
    for (int off = 32; off > 0; off >>= 1) m = fmaxf(m, __shfl_xor(m, off));
    float ssum = 0.f;
    for (int i = lane; i < 81; i += 64) ssum += expf(o[i] - m);
    for (int off = 32; off > 0; off >>= 1) ssum += __shfl_xor(ssum, off);
    float inv = 1.0f / ssum;
    int img = roi >> 9, rb = roi & 511;
    float px1 = props[roi * 4 + 0], py1 = props[roi * 4 + 1];
    float px2 = props[roi * 4 + 2], py2 = props[roi * 4 + 3];
    float w = px2 - px1, h = py2 - py1;
    float cx = px1 + 0.5f * w, cy = py1 + 0.5f * h;
    long obase = (long)img * 40960 + (long)rb * 80;
    const float DW = 4.135166556742356f;
    for (int t = lane; t < 80; t += 64) {
        int cls = t + 1;
        float score = expf(o[cls] - m) * inv;
        const float* d = o + 81 + cls * 4;
        float dx = d[0] * 0.1f, dy = d[1] * 0.1f;
        float dw = fminf(d[2] * 0.2f, DW);
        float dh = fminf(d[3] * 0.2f, DW);
        float pcx = dx * w + cx, pcy = dy * h + cy;
        float pw = expf(dw) * w, ph = expf(dh) * h;
        float x1 = pcx - 0.5f * pw, y1 = pcy - 0.5f * ph;
        float x2 = pcx + 0.5f * pw, y2 = pcy + 0.5f * ph;
        x1 = fminf(fmaxf(x1, 0.f), 800.f); y1 = fminf(fmaxf(y1, 0.f), 800.f);
        x2 = fminf(fmaxf(x2, 0.f), 800.f); y2 = fminf(fmaxf(y2, 0.f), 800.f);
        float wv = x2 - x1, hv = y2 - y1;
        long oi = obase + t;
        Boxes[oi * 4 + 0] = x1; Boxes[oi * 4 + 1] = y1;
        Boxes[oi * 4 + 2] = x2; Boxes[oi * 4 + 3] = y2;
        Scores[oi] = score;
        Valid[oi] = (score >= 0.05f && wv >= 1.0f && hv >= 1.0f) ? 1 : 0;
    }
}

// ---------------- fused compaction + greedy NMS (one block per image) ----------------
__global__ void nms_fused(const float* __restrict__ Boxes, const float* __restrict__ Scores,
                          const unsigned char* __restrict__ Valid,
                          float* __restrict__ CB, int* __restrict__ CL,
                          float* __restrict__ CSw, float* __restrict__ out) {
    int img = blockIdx.x;
    int tid = threadIdx.x;  // 256
    const int SEG = 160;    // 40960/256
    const unsigned char* V = Valid + (long)img * 40960;
    int j0 = tid * SEG;
    // vectorized count of this thread's segment (bytes are 0/1)
    const unsigned int* V4 = (const unsigned int*)(V + j0);
    int c = 0;
    #pragma unroll
    for (int k = 0; k < 40; ++k) {
        unsigned int u = V4[k];
        c += (int)((u * 0x01010101u) >> 24);
    }
    __shared__ int cnt[256];
    cnt[tid] = c;
    __syncthreads();
    for (int d = 1; d < 256; d <<= 1) {
        int v = (tid >= d) ? cnt[tid - d] : 0;
        __syncthreads();
        cnt[tid] += v;
        __syncthreads();
    }
    int pos = cnt[tid] - c;
    const float* B = Boxes + (long)img * 40960 * 4;
    const float* S = Scores + (long)img * 40960;
    float* cb = CB + (long)img * 40960 * 4;
    float* sc = CSw + (long)img * 40960;
    int* cl = CL + (long)img * 40960;
    if (c > 0) {
        for (int k = 0; k < SEG; ++k) {
            int j = j0 + k;
            if (V[j]) {
                sc[pos] = S[j];
                cb[pos * 4 + 0] = B[j * 4 + 0]; cb[pos * 4 + 1] = B[j * 4 + 1];
                cb[pos * 4 + 2] = B[j * 4 + 2]; cb[pos * 4 + 3] = B[j * 4 + 3];
                cl[pos] = (j % 80) + 1;
                ++pos;
            }
        }
    }
    int Vn = cnt[255];
    for (int i = tid; i < 400; i += 256) out[img * 400 + i] = 0.f;
    if (tid < 100) {
        out[800 + img * 100 + tid] = 0.f;
        out[1000 + img * 100 + tid] = 0.f;
        out[1200 + img * 100 + tid] = 0.f;
    }
    __syncthreads();
    __shared__ float rv[256];
    __shared__ int ri[256];
    __shared__ float selbox[4];
    const float NEG = -__builtin_inff();
    for (int det = 0; det < 100; ++det) {
        float bv = NEG; int bi = -1;
        for (int j = tid; j < Vn; j += 256) {
            float s = sc[j];
            if (s > bv) { bv = s; bi = j; }
        }
        rv[tid] = bv; ri[tid] = bi;
        __syncthreads();
        for (int off = 128; off > 0; off >>= 1) {
            if (tid < off) {
                float ov = rv[tid + off]; int oi = ri[tid + off];
                if (ov > rv[tid] ||
                    (ov == rv[tid] && oi != -1 && (ri[tid] == -1 || oi < ri[tid]))) {
                    rv[tid] = ov; ri[tid] = oi;
                }
            }
            __syncthreads();
        }
        float mval = rv[0]; int mi = ri[0];
        if (!(mval > NEG) || mi < 0) break;
        if (tid == 0) {
            out[img * 400 + det * 4 + 0] = cb[mi * 4 + 0];
            out[img * 400 + det * 4 + 1] = cb[mi * 4 + 1];
            out[img * 400 + det * 4 + 2] = cb[mi * 4 + 2];
            out[img * 400 + det * 4 + 3] = cb[mi * 4 + 3];
            out[800 + img * 100 + det] = mval;
            out[1000 + img * 100 + det] = (float)cl[mi];
            out[1200 + img * 100 + det] = 1.0f;
            selbox[0] = cb[mi * 4 + 0]; selbox[1] = cb[mi * 4 + 1];
            selbox[2] = cb[mi * 4 + 2]; selbox[3] = cb[mi * 4 + 3];
            sc[mi] = NEG;
        }
        __syncthreads();
        float bx1 = selbox[0], by1 = selbox[1], bx2 = selbox[2], by2 = selbox[3];
        float a1 = (bx2 - bx1) * (by2 - by1);
        for (int j = tid; j < Vn; j += 256) {
            float s = sc[j];
            if (s == NEG) continue;
            float x1 = fmaxf(bx1, cb[j * 4 + 0]), y1 = fmaxf(by1, cb[j * 4 + 1]);
            float x2 = fminf(bx2, cb[j * 4 + 2]), y2 = fminf(by2, cb[j * 4 + 3]);
            float iw = fmaxf(x2 - x1, 0.f), ih = fmaxf(y2 - y1, 0.f);
            float inter = iw * ih;
            float a2 = (cb[j * 4 + 2] - cb[j * 4 + 0]) * (cb[j * 4 + 3] - cb[j * 4 + 1]);
            float iou = inter / (a1 + a2 - inter + 1e-9f);
            if (iou > 0.5f) sc[j] = NEG;
        }
        __syncthreads();
    }
}

extern "C" void kernel_launch(void* const* d_in, const int* in_sizes, int n_in,
                              void* d_out, int out_size, void* d_ws, size_t ws_size,
                              hipStream_t stream) {
    const float* features  = (const float*)d_in[0];
    const float* proposals = (const float*)d_in[1];
    const float* W1 = (const float*)d_in[2];
    const float* b1 = (const float*)d_in[3];
    const float* W2 = (const float*)d_in[4];
    const float* b2 = (const float*)d_in[5];
    const float* Wc = (const float*)d_in[6];
    const float* bc = (const float*)d_in[7];
    const float* Wb = (const float*)d_in[8];
    const float* bb = (const float*)d_in[9];

    char* ws = (char*)d_ws;
    // phase A
    short* Xb    = (short*)(ws);                      // 25,690,112 B
    short* W1t   = (short*)(ws + 25690112);           // 25,690,112 B
    short* featT = (short*)(ws + 51380224);           // 2,560,000 B (dies before P)
    short* P     = (short*)(ws + 51380224);           // [4][1024][1024] bf16
    // phase B (reuses ex-Xb region after FC1)
    short* H1b   = (short*)(ws);                      // 2 MB
    short* W2t   = (short*)(ws + 2097152);            // 2 MB
    short* Wht   = (short*)(ws + 4194304);            // [512][1024] bf16, 1 MB
    short* H2b   = (short*)(ws + 5242880);            // 2 MB
    float* Obuf  = (float*)(ws + 7340032);            // [1024][448] f32
    float* Boxes = (float*)(ws + 9175040);
    float* Scores= (float*)(ws + 10485760);
    unsigned char* Valid = (unsigned char*)(ws + 10813440);
    float* CB    = (float*)(ws + 10895360);
    int*   CL    = (int*)(ws + 12206080);
    float* CSw   = (float*)(ws + 12533760);

    // NOTE: W2t/Wht written before FC1 runs — they live outside the Xb region?
    // No: W2t/Wht overlap Xb (phase B aliases phase A). So weight transposes for
    // W2/Wc/Wb CANNOT run before roi/FC1 consume Xb. Solution: transpose_all
    // writes W2t/Wht into the P region tail instead (P is 8.4MB, region has
    // 2.56MB featT + P starts after; place W2t/Wht after P).
    short* W2t_e = (short*)(ws + 51380224 + 8388608);            // +8.4MB: 2MB
    short* Wht_e = (short*)(ws + 51380224 + 8388608 + 2097152);  // 1MB (total ~62.9MB)

    transpose_all<<<15280, 256, 0, stream>>>(W1, features, W2, Wc, Wb, W1t, featT, W2t_e, Wht_e);
    roi_align_v3<<<1024, 256, 0, stream>>>(featT, proposals, Xb);

    gemm128<0><<<dim3(8, 8, 4), 256, 0, stream>>>(Xb, W1t, nullptr, nullptr, (void*)P,
                                                  1024, 1024, 12544, 49, 1024);

    reduce4_relu<<<512, 256, 0, stream>>>(P, b1, H1b);
    gemm128<1><<<dim3(8, 8, 1), 256, 0, stream>>>(H1b, W2t_e, b2, nullptr, (void*)H2b,
                                                  1024, 1024, 1024, 16, 1024);
    gemm128<2><<<dim3(4, 8, 1), 256, 0, stream>>>(H2b, Wht_e, bc, bb, (void*)Obuf,
                                                  1024, 448, 1024, 16, 448);

    head_epilogue<<<1024, 64, 0, stream>>>(Obuf, proposals, Boxes, Scores, Valid);
    nms_fused<<<2, 256, 0, stream>>>(Boxes, Scores, Valid, CB, CL, CSw, (float*)d_out);
}